// Round 3
// baseline (250.926 us; speedup 1.0000x reference)
//
#include <hip/hip_runtime.h>
#include <hip/hip_bf16.h>

typedef __attribute__((ext_vector_type(8))) short bf16x8;
typedef __attribute__((ext_vector_type(4))) float f32x4;
typedef __attribute__((ext_vector_type(8))) unsigned short ushort8;

typedef __attribute__((address_space(1))) void gvoid_as1;
typedef __attribute__((address_space(3))) void lvoid_as3;

__device__ __forceinline__ void gload_lds16(const void* g, void* l) {
  __builtin_amdgcn_global_load_lds((const gvoid_as1*)g, (lvoid_as3*)l, 16, 0, 0);
}

__device__ __forceinline__ unsigned short f2b(float f) {
  __hip_bfloat16 h = __float2bfloat16(f);
  return __builtin_bit_cast(unsigned short, h);
}

// m201 sync idiom: NO memory clobbers (they make the memory legalizer drain
// vmcnt/lgkmcnt conservatively); sched_barrier(0) pins ordering instead.
#define SBAR() __builtin_amdgcn_sched_barrier(0)
#define BAR()                                                                  \
  do {                                                                         \
    SBAR();                                                                    \
    __builtin_amdgcn_s_barrier();                                              \
    SBAR();                                                                    \
  } while (0)
#define LGKM0()                                                                \
  do {                                                                         \
    asm volatile("s_waitcnt lgkmcnt(0)");                                      \
    SBAR();                                                                    \
  } while (0)
#define VMCNT(n)                                                               \
  do {                                                                         \
    SBAR();                                                                    \
    asm volatile("s_waitcnt vmcnt(" #n ")");                                   \
    SBAR();                                                                    \
  } while (0)

// ---------------- f32 -> bf16 convert (vectorized, 4 elems/thread) ----------
__global__ __launch_bounds__(256) void cvt4(const float* __restrict__ src,
                                            unsigned short* __restrict__ dst, int n4) {
  int i = blockIdx.x * blockDim.x + threadIdx.x;
  if (i >= n4) return;
  float4 v = reinterpret_cast<const float4*>(src)[i];
  ushort4 o;
  o.x = f2b(v.x); o.y = f2b(v.y); o.z = f2b(v.z); o.w = f2b(v.w);
  reinterpret_cast<ushort4*>(dst)[i] = o;
}

// ---------------- 256x256 8-wave 4-phase MFMA GEMM (m201 structure) ---------
// C[m,n] = sum_k A[m,k]*B[n,k]  (both operands K-contiguous rows)
// EPI 0: bf16 out, += bias[n] | EPI 1: bf16 out, *= scale | EPI 2: f32 out
// LDS 128KB: [buf(2)][op A@0,B@32768][half(16KB)], rows swizzled slot^=(row&7)
template<int EPI>
__global__ __launch_bounds__(512, 2)
void gemm256(const unsigned short* __restrict__ A, int lda, long sA,
             const unsigned short* __restrict__ Bm, int ldb, long sB,
             void* __restrict__ Cv, int ldc, long sC,
             const float* __restrict__ bias, float scale, int K) {
  __shared__ char lds[131072];
  const int tid = threadIdx.x;
  const int lane = tid & 63;
  const int wv = tid >> 6;
  const int wrow = (wv >> 2) * 128;   // 0 / 128
  const int wcol = (wv & 3) * 64;     // 0 / 64 / 128 / 192
  const int lr = lane & 15;
  const int lkb = (lane >> 4) * 16;       // 16B k-oct within 64B k-slice
  const int swz = (lane & 7) << 4;        // bank swizzle (row&7 == lane&7 here)

  // bijective XCD-aware block swizzle (m204)
  const int gx = gridDim.x;
  const int nwg = gx * gridDim.y;
  const int orig = blockIdx.y * gx + blockIdx.x;
  const int xcd = orig & 7, idx = orig >> 3;
  const int q8 = nwg >> 3, r8 = nwg & 7;
  const int wg = (xcd < r8 ? xcd * (q8 + 1) : r8 * (q8 + 1) + (xcd - r8) * q8) + idx;
  const int mrow = (wg / gx) * 256;
  const int ncol = (wg % gx) * 256;

  const unsigned short* Ab = A + (size_t)blockIdx.z * sA;
  const unsigned short* Bb = Bm + (size_t)blockIdx.z * sB;

  // staging: 1024 16B segs per half-tile; seg s -> phys row r=s>>3, slot (s&7)^(r&7)
  const int s0 = tid, s1 = tid + 512;
  const int r0 = s0 >> 3, r1 = s1 >> 3;
  const int c0 = ((s0 & 7) ^ (r0 & 7)) * 8, c1 = ((s1 & 7) ^ (r1 & 7)) * 8;
  // A half-tiles interleaved by read phase: h0 = rows {0-63,128-191}
  const int arow0 = (r0 & 63) + (r0 & 64) * 2, arow1 = (r1 & 63) + (r1 & 64) * 2;
  // B half-tiles: h0 = rows {0-31,64-95,128-159,192-223}
  const int brow0 = (r0 & 31) + (r0 & 96) * 2, brow1 = (r1 & 31) + (r1 & 96) * 2;

  auto STAGE_A = [&](int half, int kt) {
    char* l = lds + ((kt & 1) << 16) + half * 16384;
    const unsigned short* g = Ab + (size_t)kt * 64;
    gload_lds16(g + (size_t)(mrow + arow0 + half * 64) * lda + c0, l + s0 * 16);
    gload_lds16(g + (size_t)(mrow + arow1 + half * 64) * lda + c1, l + s1 * 16);
  };
  auto STAGE_B = [&](int half, int kt) {
    char* l = lds + ((kt & 1) << 16) + 32768 + half * 16384;
    const unsigned short* g = Bb + (size_t)kt * 64;
    gload_lds16(g + (size_t)(ncol + brow0 + half * 32) * ldb + c0, l + s0 * 16);
    gload_lds16(g + (size_t)(ncol + brow1 + half * 32) * ldb + c1, l + s1 * 16);
  };

  f32x4 acc[8][4];
#pragma unroll
  for (int mi = 0; mi < 8; mi++)
#pragma unroll
    for (int n = 0; n < 4; n++) acc[mi][n] = (f32x4){0.f, 0.f, 0.f, 0.f};

  const int nt = K >> 6;
  // prologue: K0 {A0,B0,B1,A1}, K1 {A0,B0,B1}; K0 resident at loop entry
  STAGE_A(0, 0); STAGE_B(0, 0); STAGE_B(1, 0); STAGE_A(1, 0);
  if (nt > 1) {
    STAGE_A(0, 1); STAGE_B(0, 1); STAGE_B(1, 1);
    VMCNT(6);
  } else {
    VMCNT(0);
  }
  BAR();

  bf16x8 a0, a1, a2, a3, a4, a5, a6, a7;
  bf16x8 b0, b1, b2, b3, b4, b5, b6, b7;

  for (int t = 0; t < nt; ++t) {
    const int cur = (t & 1) << 16;
    auto LDA_ = [&](int mh, int m, int ks) -> bf16x8 {
      return *(const bf16x8*)(lds + cur + mh * 16384 +
                              (m * 16 + lr + (wrow >> 1)) * 128 + ((ks * 64 + lkb) ^ swz));
    };
    auto LDB_ = [&](int nh, int n2, int ks) -> bf16x8 {
      return *(const bf16x8*)(lds + cur + 32768 + nh * 16384 +
                              (n2 * 16 + lr + (wcol >> 1)) * 128 + ((ks * 64 + lkb) ^ swz));
    };
    // ---- phase 1: read A-h0 + B-h0; stage K(t+1).A-h1; MFMA (mh0,nh0)
    a0 = LDA_(0, 0, 0); a1 = LDA_(0, 0, 1); a2 = LDA_(0, 1, 0); a3 = LDA_(0, 1, 1);
    a4 = LDA_(0, 2, 0); a5 = LDA_(0, 2, 1); a6 = LDA_(0, 3, 0); a7 = LDA_(0, 3, 1);
    b0 = LDB_(0, 0, 0); b1 = LDB_(0, 0, 1); b2 = LDB_(0, 1, 0); b3 = LDB_(0, 1, 1);
    if (t + 1 < nt) STAGE_A(1, t + 1);
    BAR();
    LGKM0();
    __builtin_amdgcn_s_setprio(1);
    acc[0][0] = __builtin_amdgcn_mfma_f32_16x16x32_bf16(a0, b0, acc[0][0], 0, 0, 0);
    acc[0][0] = __builtin_amdgcn_mfma_f32_16x16x32_bf16(a1, b1, acc[0][0], 0, 0, 0);
    acc[0][1] = __builtin_amdgcn_mfma_f32_16x16x32_bf16(a0, b2, acc[0][1], 0, 0, 0);
    acc[0][1] = __builtin_amdgcn_mfma_f32_16x16x32_bf16(a1, b3, acc[0][1], 0, 0, 0);
    acc[1][0] = __builtin_amdgcn_mfma_f32_16x16x32_bf16(a2, b0, acc[1][0], 0, 0, 0);
    acc[1][0] = __builtin_amdgcn_mfma_f32_16x16x32_bf16(a3, b1, acc[1][0], 0, 0, 0);
    acc[1][1] = __builtin_amdgcn_mfma_f32_16x16x32_bf16(a2, b2, acc[1][1], 0, 0, 0);
    acc[1][1] = __builtin_amdgcn_mfma_f32_16x16x32_bf16(a3, b3, acc[1][1], 0, 0, 0);
    acc[2][0] = __builtin_amdgcn_mfma_f32_16x16x32_bf16(a4, b0, acc[2][0], 0, 0, 0);
    acc[2][0] = __builtin_amdgcn_mfma_f32_16x16x32_bf16(a5, b1, acc[2][0], 0, 0, 0);
    acc[2][1] = __builtin_amdgcn_mfma_f32_16x16x32_bf16(a4, b2, acc[2][1], 0, 0, 0);
    acc[2][1] = __builtin_amdgcn_mfma_f32_16x16x32_bf16(a5, b3, acc[2][1], 0, 0, 0);
    acc[3][0] = __builtin_amdgcn_mfma_f32_16x16x32_bf16(a6, b0, acc[3][0], 0, 0, 0);
    acc[3][0] = __builtin_amdgcn_mfma_f32_16x16x32_bf16(a7, b1, acc[3][0], 0, 0, 0);
    acc[3][1] = __builtin_amdgcn_mfma_f32_16x16x32_bf16(a6, b2, acc[3][1], 0, 0, 0);
    acc[3][1] = __builtin_amdgcn_mfma_f32_16x16x32_bf16(a7, b3, acc[3][1], 0, 0, 0);
    __builtin_amdgcn_s_setprio(0);
    BAR();
    // ---- phase 2: read B-h1; stage K(t+2).A-h0; MFMA (mh0,nh1)
    b4 = LDB_(1, 0, 0); b5 = LDB_(1, 0, 1); b6 = LDB_(1, 1, 0); b7 = LDB_(1, 1, 1);
    if (t + 2 < nt) STAGE_A(0, t + 2);
    BAR();
    LGKM0();
    __builtin_amdgcn_s_setprio(1);
    acc[0][2] = __builtin_amdgcn_mfma_f32_16x16x32_bf16(a0, b4, acc[0][2], 0, 0, 0);
    acc[0][2] = __builtin_amdgcn_mfma_f32_16x16x32_bf16(a1, b5, acc[0][2], 0, 0, 0);
    acc[0][3] = __builtin_amdgcn_mfma_f32_16x16x32_bf16(a0, b6, acc[0][3], 0, 0, 0);
    acc[0][3] = __builtin_amdgcn_mfma_f32_16x16x32_bf16(a1, b7, acc[0][3], 0, 0, 0);
    acc[1][2] = __builtin_amdgcn_mfma_f32_16x16x32_bf16(a2, b4, acc[1][2], 0, 0, 0);
    acc[1][2] = __builtin_amdgcn_mfma_f32_16x16x32_bf16(a3, b5, acc[1][2], 0, 0, 0);
    acc[1][3] = __builtin_amdgcn_mfma_f32_16x16x32_bf16(a2, b6, acc[1][3], 0, 0, 0);
    acc[1][3] = __builtin_amdgcn_mfma_f32_16x16x32_bf16(a3, b7, acc[1][3], 0, 0, 0);
    acc[2][2] = __builtin_amdgcn_mfma_f32_16x16x32_bf16(a4, b4, acc[2][2], 0, 0, 0);
    acc[2][2] = __builtin_amdgcn_mfma_f32_16x16x32_bf16(a5, b5, acc[2][2], 0, 0, 0);
    acc[2][3] = __builtin_amdgcn_mfma_f32_16x16x32_bf16(a4, b6, acc[2][3], 0, 0, 0);
    acc[2][3] = __builtin_amdgcn_mfma_f32_16x16x32_bf16(a5, b7, acc[2][3], 0, 0, 0);
    acc[3][2] = __builtin_amdgcn_mfma_f32_16x16x32_bf16(a6, b4, acc[3][2], 0, 0, 0);
    acc[3][2] = __builtin_amdgcn_mfma_f32_16x16x32_bf16(a7, b5, acc[3][2], 0, 0, 0);
    acc[3][3] = __builtin_amdgcn_mfma_f32_16x16x32_bf16(a6, b6, acc[3][3], 0, 0, 0);
    acc[3][3] = __builtin_amdgcn_mfma_f32_16x16x32_bf16(a7, b7, acc[3][3], 0, 0, 0);
    __builtin_amdgcn_s_setprio(0);
    BAR();
    // ---- phase 3: read A-h1 (m=4..7); stage K(t+2).B-h0; MFMA (mh1,nh0)
    a0 = LDA_(1, 0, 0); a1 = LDA_(1, 0, 1); a2 = LDA_(1, 1, 0); a3 = LDA_(1, 1, 1);
    a4 = LDA_(1, 2, 0); a5 = LDA_(1, 2, 1); a6 = LDA_(1, 3, 0); a7 = LDA_(1, 3, 1);
    if (t + 2 < nt) STAGE_B(0, t + 2);
    BAR();
    LGKM0();
    __builtin_amdgcn_s_setprio(1);
    acc[4][0] = __builtin_amdgcn_mfma_f32_16x16x32_bf16(a0, b0, acc[4][0], 0, 0, 0);
    acc[4][0] = __builtin_amdgcn_mfma_f32_16x16x32_bf16(a1, b1, acc[4][0], 0, 0, 0);
    acc[4][1] = __builtin_amdgcn_mfma_f32_16x16x32_bf16(a0, b2, acc[4][1], 0, 0, 0);
    acc[4][1] = __builtin_amdgcn_mfma_f32_16x16x32_bf16(a1, b3, acc[4][1], 0, 0, 0);
    acc[5][0] = __builtin_amdgcn_mfma_f32_16x16x32_bf16(a2, b0, acc[5][0], 0, 0, 0);
    acc[5][0] = __builtin_amdgcn_mfma_f32_16x16x32_bf16(a3, b1, acc[5][0], 0, 0, 0);
    acc[5][1] = __builtin_amdgcn_mfma_f32_16x16x32_bf16(a2, b2, acc[5][1], 0, 0, 0);
    acc[5][1] = __builtin_amdgcn_mfma_f32_16x16x32_bf16(a3, b3, acc[5][1], 0, 0, 0);
    acc[6][0] = __builtin_amdgcn_mfma_f32_16x16x32_bf16(a4, b0, acc[6][0], 0, 0, 0);
    acc[6][0] = __builtin_amdgcn_mfma_f32_16x16x32_bf16(a5, b1, acc[6][0], 0, 0, 0);
    acc[6][1] = __builtin_amdgcn_mfma_f32_16x16x32_bf16(a4, b2, acc[6][1], 0, 0, 0);
    acc[6][1] = __builtin_amdgcn_mfma_f32_16x16x32_bf16(a5, b3, acc[6][1], 0, 0, 0);
    acc[7][0] = __builtin_amdgcn_mfma_f32_16x16x32_bf16(a6, b0, acc[7][0], 0, 0, 0);
    acc[7][0] = __builtin_amdgcn_mfma_f32_16x16x32_bf16(a7, b1, acc[7][0], 0, 0, 0);
    acc[7][1] = __builtin_amdgcn_mfma_f32_16x16x32_bf16(a6, b2, acc[7][1], 0, 0, 0);
    acc[7][1] = __builtin_amdgcn_mfma_f32_16x16x32_bf16(a7, b3, acc[7][1], 0, 0, 0);
    __builtin_amdgcn_s_setprio(0);
    BAR();
    // ---- phase 4: stage K(t+2).B-h1; counted vmcnt; MFMA (mh1,nh1)
    if (t + 2 < nt) {
      STAGE_B(1, t + 2);
      VMCNT(6);
    } else {
      VMCNT(0);
    }
    BAR();
    __builtin_amdgcn_s_setprio(1);
    acc[4][2] = __builtin_amdgcn_mfma_f32_16x16x32_bf16(a0, b4, acc[4][2], 0, 0, 0);
    acc[4][2] = __builtin_amdgcn_mfma_f32_16x16x32_bf16(a1, b5, acc[4][2], 0, 0, 0);
    acc[4][3] = __builtin_amdgcn_mfma_f32_16x16x32_bf16(a0, b6, acc[4][3], 0, 0, 0);
    acc[4][3] = __builtin_amdgcn_mfma_f32_16x16x32_bf16(a1, b7, acc[4][3], 0, 0, 0);
    acc[5][2] = __builtin_amdgcn_mfma_f32_16x16x32_bf16(a2, b4, acc[5][2], 0, 0, 0);
    acc[5][2] = __builtin_amdgcn_mfma_f32_16x16x32_bf16(a3, b5, acc[5][2], 0, 0, 0);
    acc[5][3] = __builtin_amdgcn_mfma_f32_16x16x32_bf16(a2, b6, acc[5][3], 0, 0, 0);
    acc[5][3] = __builtin_amdgcn_mfma_f32_16x16x32_bf16(a3, b7, acc[5][3], 0, 0, 0);
    acc[6][2] = __builtin_amdgcn_mfma_f32_16x16x32_bf16(a4, b4, acc[6][2], 0, 0, 0);
    acc[6][2] = __builtin_amdgcn_mfma_f32_16x16x32_bf16(a5, b5, acc[6][2], 0, 0, 0);
    acc[6][3] = __builtin_amdgcn_mfma_f32_16x16x32_bf16(a4, b6, acc[6][3], 0, 0, 0);
    acc[6][3] = __builtin_amdgcn_mfma_f32_16x16x32_bf16(a5, b7, acc[6][3], 0, 0, 0);
    acc[7][2] = __builtin_amdgcn_mfma_f32_16x16x32_bf16(a6, b4, acc[7][2], 0, 0, 0);
    acc[7][2] = __builtin_amdgcn_mfma_f32_16x16x32_bf16(a7, b5, acc[7][2], 0, 0, 0);
    acc[7][3] = __builtin_amdgcn_mfma_f32_16x16x32_bf16(a6, b6, acc[7][3], 0, 0, 0);
    acc[7][3] = __builtin_amdgcn_mfma_f32_16x16x32_bf16(a7, b7, acc[7][3], 0, 0, 0);
    __builtin_amdgcn_s_setprio(0);
    BAR();
  }

  // epilogue: C/D layout col=lane&15, row=(lane>>4)*4+reg  [m89-verified]
  const int r0e = mrow + wrow + (lane >> 4) * 4;
  const int c0e = ncol + wcol + lr;
  if (EPI == 2) {
    float* C = (float*)Cv + (size_t)blockIdx.z * sC;
#pragma unroll
    for (int mi = 0; mi < 8; mi++)
#pragma unroll
      for (int n = 0; n < 4; n++)
#pragma unroll
        for (int j = 0; j < 4; j++)
          C[(size_t)(r0e + (mi >> 2) * 64 + (mi & 3) * 16 + j) * ldc + (c0e + n * 16)] =
              acc[mi][n][j];
  } else {
    unsigned short* C = (unsigned short*)Cv + (size_t)blockIdx.z * sC;
    float bv[4];
#pragma unroll
    for (int n = 0; n < 4; n++) bv[n] = (EPI == 0) ? bias[c0e + n * 16] : 0.f;
#pragma unroll
    for (int mi = 0; mi < 8; mi++)
#pragma unroll
      for (int n = 0; n < 4; n++)
#pragma unroll
        for (int j = 0; j < 4; j++) {
          float v = acc[mi][n][j];
          v = (EPI == 0) ? (v + bv[n]) : (v * scale);
          C[(size_t)(r0e + (mi >> 2) * 64 + (mi & 3) * 16 + j) * ldc + (c0e + n * 16)] = f2b(v);
        }
  }
}

// ---------------- V transpose: vt[b][e][l] = qkv[b*L+l][1536+e] -------------
__global__ __launch_bounds__(256) void transpose_v(const unsigned short* __restrict__ qkv,
                                                   unsigned short* __restrict__ vt) {
  __shared__ unsigned short t[32][33];
  const int b = blockIdx.z;
  const int l0 = blockIdx.x * 32, e0 = blockIdx.y * 32;
  const int tx = threadIdx.x & 31, ty = threadIdx.x >> 5;  // ty 0..7
#pragma unroll
  for (int j = 0; j < 4; j++)
    t[ty + j * 8][tx] = qkv[((size_t)b * 2048 + l0 + ty + j * 8) * 2304 + 1536 + e0 + tx];
  __syncthreads();
#pragma unroll
  for (int j = 0; j < 4; j++)
    vt[((size_t)b * 768 + e0 + ty + j * 8) * 2048 + l0 + tx] = t[tx][ty + j * 8];
}

// ---------------- row softmax in-place on bf16 scores -----------------------
__global__ __launch_bounds__(256) void softmax_rows(unsigned short* __restrict__ S) {
  const int tid = threadIdx.x;
  unsigned short* p = S + (size_t)blockIdx.x * 2048;
  ushort8 u = reinterpret_cast<const ushort8*>(p)[tid];
  float v[8];
#pragma unroll
  for (int j = 0; j < 8; j++)
    v[j] = __builtin_bit_cast(float, (unsigned)u[j] << 16);
  float m = v[0];
#pragma unroll
  for (int j = 1; j < 8; j++) m = fmaxf(m, v[j]);
  for (int off = 32; off; off >>= 1) m = fmaxf(m, __shfl_xor(m, off));
  __shared__ float smax[4], ssum[4];
  const int wv = tid >> 6, lane = tid & 63;
  if (lane == 0) smax[wv] = m;
  __syncthreads();
  m = fmaxf(fmaxf(smax[0], smax[1]), fmaxf(smax[2], smax[3]));
  float e[8];
  float s = 0.f;
#pragma unroll
  for (int j = 0; j < 8; j++) {
    e[j] = exp2f((v[j] - m) * 1.4426950408889634f);
    s += e[j];
  }
  for (int off = 32; off; off >>= 1) s += __shfl_xor(s, off);
  if (lane == 0) ssum[wv] = s;
  __syncthreads();
  s = (ssum[0] + ssum[1]) + (ssum[2] + ssum[3]);
  float inv = 1.0f / s;
  ushort8 o;
#pragma unroll
  for (int j = 0; j < 8; j++) o[j] = f2b(e[j] * inv);
  reinterpret_cast<ushort8*>(p)[tid] = o;
}

// ---------------- host ------------------------------------------------------
extern "C" void kernel_launch(void* const* d_in, const int* in_sizes, int n_in,
                              void* d_out, int out_size, void* d_ws, size_t ws_size,
                              hipStream_t stream) {
  const float* x = (const float*)d_in[0];
  const float* W = (const float*)d_in[1];
  const float* bias = (const float*)d_in[2];
  float* out = (float*)d_out;
  char* ws = (char*)d_ws;

  unsigned short* xb = (unsigned short*)(ws);
  unsigned short* wb = (unsigned short*)(ws + 25165824);
  unsigned short* qkv = (unsigned short*)(ws + 28704768);
  unsigned short* vt = (unsigned short*)(ws + 104202240);
  unsigned short* S = (unsigned short*)(ws + 129368064);
  const float scale = 0.03608439182435161f;  // 768^-0.5

  cvt4<<<12288, 256, 0, stream>>>(x, xb, 3145728);
  cvt4<<<1728, 256, 0, stream>>>(W, wb, 442368);
  // QKV = x @ W^T + b : M=16384 N=2304 K=768
  gemm256<0><<<dim3(9, 64, 1), 512, 0, stream>>>(xb, 768, 0, wb, 768, 0,
                                                 qkv, 2304, 0, bias, 0.f, 768);
  transpose_v<<<dim3(64, 24, 8), 256, 0, stream>>>(qkv, vt);

  bool batched = ws_size >= (129368064UL + 67108864UL);
  if (batched) {
    // S = scale * Q @ K^T per batch: M=N=2048 K=768
    gemm256<1><<<dim3(8, 8, 8), 512, 0, stream>>>(
        qkv, 2304, 2048L * 2304, qkv + 768, 2304, 2048L * 2304,
        S, 2048, 2048L * 2048, nullptr, scale, 768);
    softmax_rows<<<16384, 256, 0, stream>>>(S);
    // out = P @ V : M=2048 N=768 K=2048
    gemm256<2><<<dim3(3, 8, 8), 512, 0, stream>>>(
        S, 2048, 2048L * 2048, vt, 2048, 768L * 2048,
        out, 768, 2048L * 768, nullptr, 0.f, 2048);
  } else {
    for (int b = 0; b < 8; b++) {
      const unsigned short* qb = qkv + (size_t)b * 2048 * 2304;
      gemm256<1><<<dim3(8, 8, 1), 512, 0, stream>>>(
          qb, 2304, 0, qb + 768, 2304, 0, S, 2048, 0, nullptr, scale, 768);
      softmax_rows<<<2048, 256, 0, stream>>>(S);
      gemm256<2><<<dim3(3, 8, 1), 512, 0, stream>>>(
          S, 2048, 0, vt + (size_t)b * 768 * 2048, 2048, 0,
          out + (size_t)b * 2048 * 768, 768, 0, nullptr, 0.f, 2048);
    }
  }
}

// Round 4
// 221.612 us; speedup vs baseline: 1.1323x; 1.1323x over previous
//
#include <hip/hip_runtime.h>
#include <hip/hip_bf16.h>

typedef __attribute__((ext_vector_type(8))) short bf16x8;
typedef __attribute__((ext_vector_type(4))) float f32x4;
typedef __attribute__((ext_vector_type(8))) unsigned short ushort8;

typedef __attribute__((address_space(1))) void gvoid_as1;
typedef __attribute__((address_space(3))) void lvoid_as3;

__device__ __forceinline__ void gload_lds16(const void* g, void* l) {
  __builtin_amdgcn_global_load_lds((const gvoid_as1*)g, (lvoid_as3*)l, 16, 0, 0);
}

__device__ __forceinline__ unsigned short f2b(float f) {
  __hip_bfloat16 h = __float2bfloat16(f);
  return __builtin_bit_cast(unsigned short, h);
}

// ---------------- f32 -> bf16 convert, x and W in one dispatch --------------
__global__ __launch_bounds__(256) void cvt_all(const float* __restrict__ x,
                                               const float* __restrict__ W,
                                               unsigned short* __restrict__ xb,
                                               unsigned short* __restrict__ wb) {
  int i = blockIdx.x * blockDim.x + threadIdx.x;
  const float* src;
  unsigned short* dst;
  int j;
  if (i < 3145728) {            // x: 8*2048*768 f32 = 3145728 float4
    src = x; dst = xb; j = i;
  } else {                      // W: 2304*768 = 442368 float4
    src = W; dst = wb; j = i - 3145728;
    if (j >= 442368) return;
  }
  float4 v = reinterpret_cast<const float4*>(src)[j];
  ushort4 o;
  o.x = f2b(v.x); o.y = f2b(v.y); o.z = f2b(v.z); o.w = f2b(v.w);
  reinterpret_cast<ushort4*>(dst)[j] = o;
}

// ---------------- 128x128 BK=64 MFMA GEMM (m97 structure, multi-block/CU) ---
// C[m,n] = sum_k A[m,k]*B[n,k]  (both operands K-contiguous rows)
// EPI 0: QKV epilogue — bf16 out; +bias; cols<768 *=scale (Q); cols>=1536
//        written TRANSPOSED to vt (V) instead of C.
// EPI 1: bf16 out plain (scores; scale folded into Q already)
// EPI 2: f32 out direct (attention output)
// LDS 32KB: lsA [128 rows][8 slots of 16B], slot ^= row&7 (T2, both-sides).
template<int EPI>
__global__ __launch_bounds__(256, 2)
void gemm128(const unsigned short* __restrict__ A, int lda, long sA,
             const unsigned short* __restrict__ Bm, int ldb, long sB,
             void* __restrict__ Cv, int ldc, long sC,
             const float* __restrict__ bias, float scale,
             unsigned short* __restrict__ vt, int K) {
  __shared__ unsigned short lsAB[16384];  // A @0 (16KB), B @8192 (16KB)
  char* const lds = (char*)lsAB;
  const int tid = threadIdx.x;
  const int lane = tid & 63;
  const int wv = tid >> 6;
  const int wr = (wv >> 1) * 64;
  const int wc = (wv & 1) * 64;
  const int lr = lane & 15;
  const int lkb = (lane >> 4) * 16;   // 16B k-oct within 64B k-slice
  const int swz = (lane & 7) << 4;    // read-side XOR (row&7 == lr&7)

  // bijective XCD-aware swizzle on the xy-plane (all grids: nwg%8==0)
  const int gx = gridDim.x;
  const int nwg = gx * gridDim.y;
  const int orig = blockIdx.y * gx + blockIdx.x;
  const int xcd = orig & 7, idx = orig >> 3;
  const int q8 = nwg >> 3, r8 = nwg & 7;
  const int wg = (xcd < r8 ? xcd * (q8 + 1) : r8 * (q8 + 1) + (xcd - r8) * q8) + idx;
  const int brow = (wg / gx) * 128;
  const int bcol = (wg % gx) * 128;

  const unsigned short* Ab = A + (size_t)blockIdx.z * sA;
  const unsigned short* Bb = Bm + (size_t)blockIdx.z * sB;

  f32x4 acc[4][4];
#pragma unroll
  for (int m = 0; m < 4; m++)
#pragma unroll
    for (int n = 0; n < 4; n++) acc[m][n] = (f32x4){0.f, 0.f, 0.f, 0.f};

  for (int kk = 0; kk < K; kk += 64) {
    // stage 128x64 A and B tiles: 1024 16B segs each, 4 per thread per op.
    // seg s -> row r=s>>3, pre-swizzled global col ((s&7)^(r&7))*8; LDS linear.
#pragma unroll
    for (int j = 0; j < 4; j++) {
      const int s = tid + j * 256;
      const int r = s >> 3;
      const int c = ((s & 7) ^ (r & 7)) * 8;
      gload_lds16(Ab + (size_t)(brow + r) * lda + kk + c, lds + s * 16);
      gload_lds16(Bb + (size_t)(bcol + r) * ldb + kk + c, lds + 16384 + s * 16);
    }
    __syncthreads();  // drains vmcnt; cross-block overlap hides the stall
    bf16x8 af[4][2], bfr[4][2];
#pragma unroll
    for (int m = 0; m < 4; m++)
#pragma unroll
      for (int ks = 0; ks < 2; ks++)
        af[m][ks] = *(const bf16x8*)(lds + (wr + m * 16 + lr) * 128 +
                                     ((ks * 64 + lkb) ^ swz));
#pragma unroll
    for (int n = 0; n < 4; n++)
#pragma unroll
      for (int ks = 0; ks < 2; ks++)
        bfr[n][ks] = *(const bf16x8*)(lds + 16384 + (wc + n * 16 + lr) * 128 +
                                      ((ks * 64 + lkb) ^ swz));
#pragma unroll
    for (int m = 0; m < 4; m++)
#pragma unroll
      for (int n = 0; n < 4; n++) {
        acc[m][n] = __builtin_amdgcn_mfma_f32_16x16x32_bf16(af[m][0], bfr[n][0], acc[m][n], 0, 0, 0);
        acc[m][n] = __builtin_amdgcn_mfma_f32_16x16x32_bf16(af[m][1], bfr[n][1], acc[m][n], 0, 0, 0);
      }
    __syncthreads();  // protect LDS before next-iter staging
  }

  // ---- epilogue. C/D frag layout: col=lane&15, row=(lane>>4)*4+reg ----
  if (EPI == 2) {
    // f32 direct scalar stores (64B segments per 16-lane group — fine)
    float* C = (float*)Cv + (size_t)blockIdx.z * sC;
    const int r0e = brow + wr + (lane >> 4) * 4;
    const int c0e = bcol + wc + lr;
#pragma unroll
    for (int m = 0; m < 4; m++)
#pragma unroll
      for (int n = 0; n < 4; n++)
#pragma unroll
        for (int j = 0; j < 4; j++)
          C[(size_t)(r0e + m * 16 + j) * ldc + (c0e + n * 16)] = acc[m][n][j];
  } else {
    // bf16 path: round-trip through LDS (reuse 32KB) for ushort8 stores.
    const bool isV = (EPI == 0) && (bcol >= 1536);
    const bool isQ = (EPI == 0) && (bcol < 768);
    float bv[4];
    if (EPI == 0) {
#pragma unroll
      for (int n = 0; n < 4; n++) bv[n] = bias[bcol + wc + n * 16 + lr];
    }
    // write acc -> LDS tile [128][128] bf16, slot ^= (row&15)
#pragma unroll
    for (int m = 0; m < 4; m++)
#pragma unroll
      for (int n = 0; n < 4; n++)
#pragma unroll
        for (int j = 0; j < 4; j++) {
          float v = acc[m][n][j];
          if (EPI == 0) {
            v += bv[n];
            if (isQ) v *= scale;
          }
          const int R = wr + (lane >> 4) * 4 + m * 16 + j;  // local row (l)
          const int Cc = wc + n * 16 + lr;                  // local col (e)
          const int row_ = isV ? Cc : R;
          const int col_ = isV ? R : Cc;
          *(unsigned short*)(lds + row_ * 256 +
                             ((col_ * 2) ^ ((row_ & 15) << 4))) = f2b(v);
        }
    __syncthreads();
    // read back rows, 16B chunks; chunk (row, sl) holds global cols sl*8..+8
    if (isV) {
      const int b = brow >> 11;        // batch (BM=128 never straddles)
      const int l0 = brow & 2047;
      const int e0 = bcol - 1536;
      unsigned short* dst = vt + ((size_t)b * 768 + e0) * 2048 + l0;
#pragma unroll
      for (int i = 0; i < 8; i++) {
        const int id = tid + i * 256;
        const int row = id >> 4, sl = id & 15;
        ushort8 vv = *(const ushort8*)(lds + row * 256 +
                                       ((sl * 16) ^ ((row & 15) << 4)));
        *(ushort8*)(dst + (size_t)row * 2048 + sl * 8) = vv;
      }
    } else {
      unsigned short* C = (unsigned short*)Cv + (size_t)blockIdx.z * sC +
                          (size_t)brow * ldc + bcol;
#pragma unroll
      for (int i = 0; i < 8; i++) {
        const int id = tid + i * 256;
        const int row = id >> 4, sl = id & 15;
        ushort8 vv = *(const ushort8*)(lds + row * 256 +
                                       ((sl * 16) ^ ((row & 15) << 4)));
        *(ushort8*)(C + (size_t)row * ldc + sl * 8) = vv;
      }
    }
  }
}

// ---------------- row softmax in-place on bf16 scores -----------------------
__global__ __launch_bounds__(256) void softmax_rows(unsigned short* __restrict__ S) {
  const int tid = threadIdx.x;
  unsigned short* p = S + (size_t)blockIdx.x * 2048;
  ushort8 u = reinterpret_cast<const ushort8*>(p)[tid];
  float v[8];
#pragma unroll
  for (int j = 0; j < 8; j++)
    v[j] = __builtin_bit_cast(float, (unsigned)u[j] << 16);
  float m = v[0];
#pragma unroll
  for (int j = 1; j < 8; j++) m = fmaxf(m, v[j]);
  for (int off = 32; off; off >>= 1) m = fmaxf(m, __shfl_xor(m, off));
  __shared__ float smax[4], ssum[4];
  const int wv = tid >> 6, lane = tid & 63;
  if (lane == 0) smax[wv] = m;
  __syncthreads();
  m = fmaxf(fmaxf(smax[0], smax[1]), fmaxf(smax[2], smax[3]));
  float e[8];
  float s = 0.f;
#pragma unroll
  for (int j = 0; j < 8; j++) {
    e[j] = exp2f((v[j] - m) * 1.4426950408889634f);
    s += e[j];
  }
  for (int off = 32; off; off >>= 1) s += __shfl_xor(s, off);
  if (lane == 0) ssum[wv] = s;
  __syncthreads();
  s = (ssum[0] + ssum[1]) + (ssum[2] + ssum[3]);
  float inv = 1.0f / s;
  ushort8 o;
#pragma unroll
  for (int j = 0; j < 8; j++) o[j] = f2b(e[j] * inv);
  reinterpret_cast<ushort8*>(p)[tid] = o;
}

// ---------------- host ------------------------------------------------------
extern "C" void kernel_launch(void* const* d_in, const int* in_sizes, int n_in,
                              void* d_out, int out_size, void* d_ws, size_t ws_size,
                              hipStream_t stream) {
  const float* x = (const float*)d_in[0];
  const float* W = (const float*)d_in[1];
  const float* bias = (const float*)d_in[2];
  float* out = (float*)d_out;
  char* ws = (char*)d_ws;

  unsigned short* xb = (unsigned short*)(ws);
  unsigned short* wb = (unsigned short*)(ws + 25165824);
  unsigned short* qkv = (unsigned short*)(ws + 28704768);
  unsigned short* vt = (unsigned short*)(ws + 104202240);
  unsigned short* S = (unsigned short*)(ws + 129368064);
  const float scale = 0.03608439182435161f;  // 768^-0.5

  cvt_all<<<14016, 256, 0, stream>>>(x, W, xb, wb);
  // QKV = x @ W^T + b : M=16384 N=2304 K=768; Q scaled; V written to vt^T
  gemm128<0><<<dim3(18, 128, 1), 256, 0, stream>>>(
      xb, 768, 0, wb, 768, 0, qkv, 2304, 0, bias, scale, vt, 768);

  bool batched = ws_size >= (129368064UL + 67108864UL);
  if (batched) {
    // S = Q @ K^T per batch (scale already in Q): M=N=2048 K=768
    gemm128<1><<<dim3(16, 16, 8), 256, 0, stream>>>(
        qkv, 2304, 2048L * 2304, qkv + 768, 2304, 2048L * 2304,
        S, 2048, 2048L * 2048, nullptr, 1.f, nullptr, 768);
    softmax_rows<<<16384, 256, 0, stream>>>(S);
    // out = P @ V : M=2048 N=768 K=2048
    gemm128<2><<<dim3(6, 16, 8), 256, 0, stream>>>(
        S, 2048, 2048L * 2048, vt, 2048, 768L * 2048,
        out, 768, 2048L * 768, nullptr, 1.f, nullptr, 2048);
  } else {
    for (int b = 0; b < 8; b++) {
      const unsigned short* qb = qkv + (size_t)b * 2048 * 2304;
      gemm128<1><<<dim3(16, 16, 1), 256, 0, stream>>>(
          qb, 2304, 0, qb + 768, 2304, 0, S, 2048, 0, nullptr, 1.f, nullptr, 768);
      softmax_rows<<<2048, 256, 0, stream>>>(S);
      gemm128<2><<<dim3(6, 16, 1), 256, 0, stream>>>(
          S, 2048, 0, vt + (size_t)b * 768 * 2048, 2048, 0,
          out + (size_t)b * 2048 * 768, 768, 0, nullptr, 1.f, nullptr, 2048);
    }
  }
}